// Round 8
// baseline (1886.435 us; speedup 1.0000x reference)
//
#include <hip/hip_runtime.h>
#include <hip/hip_fp16.h>

#define FD 128            // feature dim
#define BSHIFT 9          // bucket = dst >> 9  (512 nodes per bucket)
#define BNODES 512
#define CAP 20480         // per-bucket csr capacity (avg 16384, +32 sigma)
#define GRID 1024         // 4 blocks/CU x 256 CU -> all co-resident
#define NT 256

typedef _Float16 half8 __attribute__((ext_vector_type(8)));
typedef float floatx4 __attribute__((ext_vector_type(4)));

struct Params {
    const float* x;
    const int* src;
    const int* dst;
    const float* W1l; const float* W1r;
    const float* W2l; const float* W2r;
    const float* W3l; const float* W3r;
    const float* b1; const float* b2; const float* b3;
    float* out;
    int* cursor; int* sorted; int* row_ptr; int* deg; float* rdeg; int* csr;
    int* bar;                                   // software grid-barrier counters
    __half* xb; __half* h1; __half* h2; __half* aggB;
    half8* wf;
    int N, E, B;
};

union SharedU {
    struct { int cnt[256]; int base[256]; } sc;   // scatter
    struct { int dl[BNODES]; int ps[256]; } bb;   // build
};

// ---------------------------------------------------------------------------
// Software grid barrier: monotonic counter per barrier site. Residency is
// guaranteed (GRID == 4 blocks/CU capacity), so no deadlock; spin is capped
// anyway. threadfence = device-scope release/acquire (wbL2 / invL2) so
// non-atomic stores are visible across XCDs (guide: G16).
// ---------------------------------------------------------------------------
__device__ __forceinline__ void gbar(int* cnt, int nblk) {
    __syncthreads();
    if (threadIdx.x == 0) {
        __threadfence();
        atomicAdd(cnt, 1);
        int spins = 0;
        while (__hip_atomic_load(cnt, __ATOMIC_RELAXED, __HIP_MEMORY_SCOPE_AGENT) < nblk) {
            __builtin_amdgcn_s_sleep(2);
            if (++spins > (1 << 24)) break;      // safety valve: never hang
        }
        __threadfence();
    }
    __syncthreads();
}

// ---------------------------------------------------------------------------
// P0a: fp32 -> f16 row-major feature conversion (grid-stride)
// ---------------------------------------------------------------------------
__device__ void phase_tof16(const Params& p, int gid, int total) {
    int n4 = p.N * FD / 4;
    const float4* in = (const float4*)p.x;
    __half2* out = (__half2*)p.xb;
    for (int i = gid; i < n4; i += total) {
        float4 v = in[i];
        out[2 * i + 0] = __floats2half2_rn(v.x, v.y);
        out[2 * i + 1] = __floats2half2_rn(v.z, v.w);
    }
}

// ---------------------------------------------------------------------------
// P0b: pack all 3 layers' [Wl;Wr] into MFMA B-frag order (12288 items)
// ---------------------------------------------------------------------------
__device__ void phase_pack(const Params& p, int gid) {
    if (gid >= 12288) return;
    int t = gid;
    int layer = t >> 12;
    int li = t & 4095;
    const float* Wl = (layer == 0) ? p.W1l : (layer == 1) ? p.W2l : p.W3l;
    const float* Wr = (layer == 0) ? p.W1r : (layer == 1) ? p.W2r : p.W3r;
    int lane = li & 63;
    int kt = (li >> 6) & 7;
    int nt = li >> 9;
    int n = nt * 16 + (lane & 15);
    int kq = kt * 32 + ((lane >> 4) & 3) * 8;
    half8 f;
#pragma unroll
    for (int j = 0; j < 8; ++j) {
        int k = kq + j;
        float v = (k < 128) ? Wl[n * 128 + k] : Wr[n * 128 + (k - 128)];
        f[j] = (_Float16)v;
    }
    p.wf[t] = f;
}

// ---------------------------------------------------------------------------
// P1: bucketed scatter with block-level reservation (R1-proven structure).
// Entry packed as (local_dst << 17) | src  (src < 2^17, local_dst < 512).
// ---------------------------------------------------------------------------
__device__ void phase_scatter(const Params& p, int* cnt, int* base) {
    int t = threadIdx.x;
    cnt[t] = 0;
    __syncthreads();
    int chunk = (p.E + GRID - 1) / GRID;
    int s0 = blockIdx.x * chunk;
    int s1 = s0 + chunk; if (s1 > p.E) s1 = p.E;
    for (int e = s0 + t; e < s1; e += NT)
        atomicAdd(&cnt[p.dst[e] >> BSHIFT], 1);
    __syncthreads();
    int c = cnt[t];
    if (c > 0) base[t] = atomicAdd(&p.cursor[t], c);
    cnt[t] = 0;
    __syncthreads();
    for (int e = s0 + t; e < s1; e += NT) {
        int d = p.dst[e];
        int b = d >> BSHIFT;
        int pp = base[b] + atomicAdd(&cnt[b], 1);
        if (pp < CAP) p.sorted[(size_t)b * CAP + pp] = ((d & (BNODES - 1)) << 17) | p.src[e];
    }
}

// ---------------------------------------------------------------------------
// P2: per-bucket CSR build (one bucket per block; blocks >= B skip).
// ---------------------------------------------------------------------------
__device__ void phase_build(const Params& p, int* dl, int* ps) {
    int b = blockIdx.x;
    int nbase = b << BSHIFT;
    int t = threadIdx.x;
    int cnt = p.cursor[b]; if (cnt > CAP) cnt = CAP;
    dl[t] = 0; dl[t + 256] = 0;
    __syncthreads();
    const int* se = p.sorted + (size_t)b * CAP;
    for (int e = t; e < cnt; e += NT)
        atomicAdd(&dl[((unsigned)se[e]) >> 17], 1);
    __syncthreads();
    int a0 = dl[2 * t], a1 = dl[2 * t + 1];
    ps[t] = a0 + a1;
    __syncthreads();
    for (int off = 1; off < 256; off <<= 1) {
        int v = (t >= off) ? ps[t - off] : 0;
        __syncthreads();
        ps[t] += v;
        __syncthreads();
    }
    int pre = ps[t] - a0 - a1;
    int cb = b * CAP;
    int n0 = nbase + 2 * t, n1 = n0 + 1;
    if (n0 < p.N) {
        p.row_ptr[n0] = cb + pre;
        p.deg[n0] = a0;
        p.rdeg[n0] = 1.0f / (float)(a0 > 1 ? a0 : 1);
    }
    if (n1 < p.N) {
        p.row_ptr[n1] = cb + pre + a0;
        p.deg[n1] = a1;
        p.rdeg[n1] = 1.0f / (float)(a1 > 1 ? a1 : 1);
    }
    dl[2 * t] = pre;
    dl[2 * t + 1] = pre + a0;
    __syncthreads();
    for (int e = t; e < cnt; e += NT) {
        int v = se[e];
        int pp = atomicAdd(&dl[((unsigned)v) >> 17], 1);
        p.csr[cb + pp] = v & 0x1FFFF;
    }
}

// ---------------------------------------------------------------------------
// Mean aggregation (R1-verified structure, grid-strided): one wave per dst
// node; 16-lane group per edge, half8 loads -> 4 edges per VMEM instruction,
// 4 gathers in flight per wave. Cross-group reduce via __shfl_xor(16,32).
// ---------------------------------------------------------------------------
__device__ void phase_agg(const Params& p, const __half* h, __half* out) {
    int wave = threadIdx.x >> 6;
    int lane = threadIdx.x & 63;
    int g = lane >> 4;
    int l16 = lane & 15;
    for (int node = blockIdx.x * 4 + wave; node < p.N; node += GRID * 4) {
        int start = p.row_ptr[node];
        int d = p.deg[node];
        float acc[8];
#pragma unroll
        for (int j = 0; j < 8; ++j) acc[j] = 0.f;
        int i = 0;
        for (; i + 16 <= d; i += 16) {
            int s0 = p.csr[start + i + 0 + g];
            int s1 = p.csr[start + i + 4 + g];
            int s2 = p.csr[start + i + 8 + g];
            int s3 = p.csr[start + i + 12 + g];
            half8 v0 = *(const half8*)(h + (size_t)s0 * FD + l16 * 8);
            half8 v1 = *(const half8*)(h + (size_t)s1 * FD + l16 * 8);
            half8 v2 = *(const half8*)(h + (size_t)s2 * FD + l16 * 8);
            half8 v3 = *(const half8*)(h + (size_t)s3 * FD + l16 * 8);
#pragma unroll
            for (int j = 0; j < 8; ++j) acc[j] += (float)v0[j];
#pragma unroll
            for (int j = 0; j < 8; ++j) acc[j] += (float)v1[j];
#pragma unroll
            for (int j = 0; j < 8; ++j) acc[j] += (float)v2[j];
#pragma unroll
            for (int j = 0; j < 8; ++j) acc[j] += (float)v3[j];
        }
        for (; i + 4 <= d; i += 4) {
            int s = p.csr[start + i + g];
            half8 v = *(const half8*)(h + (size_t)s * FD + l16 * 8);
#pragma unroll
            for (int j = 0; j < 8; ++j) acc[j] += (float)v[j];
        }
        if (i + g < d) {
            int s = p.csr[start + i + g];
            half8 v = *(const half8*)(h + (size_t)s * FD + l16 * 8);
#pragma unroll
            for (int j = 0; j < 8; ++j) acc[j] += (float)v[j];
        }
#pragma unroll
        for (int j = 0; j < 8; ++j) {
            acc[j] += __shfl_xor(acc[j], 16, 64);
            acc[j] += __shfl_xor(acc[j], 32, 64);
        }
        if (g == 0) {
            float r = p.rdeg[node];
            half8 o;
#pragma unroll
            for (int j = 0; j < 8; ++j) o[j] = (_Float16)(acc[j] * r);
            *(half8*)(out + (size_t)node * FD + l16 * 8) = o;
        }
    }
}

// ---------------------------------------------------------------------------
// MFMA GEMM phase (grid-strided tiles): out = cat(A,H) @ Wcat^T + b (+ReLU).
// ---------------------------------------------------------------------------
template <int OUT_FP32>
__device__ void phase_gemm(const __half* A, const __half* H, const half8* Wfrag,
                           const float* bias, void* outp, int n, int do_relu) {
    int tid = threadIdx.x;
    int wave = tid >> 6;
    int lane = tid & 63;
    int quad = (lane >> 4) & 3;
    int l16 = lane & 15;
    int ntiles = (n + 127) / 128;
    for (int tile = blockIdx.x; tile < ntiles; tile += GRID) {
        long tilebase = (long)tile * 128;
        long r0 = tilebase + wave * 32 + l16;
        long r1 = r0 + 16;
        long ra = (r0 < n) ? r0 : (n - 1);
        long rb = (r1 < n) ? r1 : (n - 1);

        floatx4 acc[2][8];
#pragma unroll
        for (int m = 0; m < 2; ++m)
#pragma unroll
            for (int nt = 0; nt < 8; ++nt) acc[m][nt] = (floatx4){0.f, 0.f, 0.f, 0.f};

#pragma unroll
        for (int kt = 0; kt < 8; ++kt) {
            const __half* srcp = (kt < 4) ? A : H;
            int koff = (kt & 3) * 32 + quad * 8;
            half8 a0 = *(const half8*)(srcp + (size_t)ra * FD + koff);
            half8 a1 = *(const half8*)(srcp + (size_t)rb * FD + koff);
#pragma unroll
            for (int nt = 0; nt < 8; ++nt) {
                half8 b = Wfrag[(size_t)(nt * 8 + kt) * 64 + lane];
                acc[0][nt] = __builtin_amdgcn_mfma_f32_16x16x32_f16(a0, b, acc[0][nt], 0, 0, 0);
                acc[1][nt] = __builtin_amdgcn_mfma_f32_16x16x32_f16(a1, b, acc[1][nt], 0, 0, 0);
            }
        }

#pragma unroll
        for (int m = 0; m < 2; ++m) {
#pragma unroll
            for (int nt = 0; nt < 8; ++nt) {
                int col = nt * 16 + l16;
                float bv = bias[col];
#pragma unroll
                for (int r = 0; r < 4; ++r) {
                    long row = tilebase + wave * 32 + m * 16 + quad * 4 + r;
                    if (row < n) {
                        float v = acc[m][nt][r] + bv;
                        if (do_relu) v = v > 0.f ? v : 0.f;
                        if (OUT_FP32)
                            ((float*)outp)[row * FD + col] = v;
                        else
                            ((__half*)outp)[row * FD + col] = __float2half_rn(v);
                    }
                }
            }
        }
    }
}

// ---------------------------------------------------------------------------
// Single persistent kernel: prep -> scatter -> build -> (agg -> gemm) x3,
// separated by software grid barriers. Replaces 11 dispatches (~27 us
// overhead each by the R1-R6 invariant) with 1 (+1 tiny memset).
// ---------------------------------------------------------------------------
__global__ __launch_bounds__(256, 4) void fused_all(Params p) {
    __shared__ SharedU sh;
    int gid = blockIdx.x * NT + threadIdx.x;
    int total = GRID * NT;

    // P0: convert + pack + zero cursors
    phase_tof16(p, gid, total);
    phase_pack(p, gid);
    if (gid < 256) p.cursor[gid] = 0;
    gbar(p.bar + 0, GRID);
    // P1: scatter
    phase_scatter(p, sh.sc.cnt, sh.sc.base);
    gbar(p.bar + 1, GRID);
    // P2: build
    if (blockIdx.x < (unsigned)p.B) phase_build(p, sh.bb.dl, sh.bb.ps);
    gbar(p.bar + 2, GRID);
    // layer 1
    phase_agg(p, p.xb, p.aggB);
    gbar(p.bar + 3, GRID);
    phase_gemm<0>(p.aggB, p.xb, p.wf, p.b1, p.h1, p.N, 1);
    gbar(p.bar + 4, GRID);
    // layer 2
    phase_agg(p, p.h1, p.aggB);
    gbar(p.bar + 5, GRID);
    phase_gemm<0>(p.aggB, p.h1, p.wf + 4096, p.b2, p.h2, p.N, 1);
    gbar(p.bar + 6, GRID);
    // layer 3
    phase_agg(p, p.h2, p.aggB);
    gbar(p.bar + 7, GRID);
    phase_gemm<1>(p.aggB, p.h2, p.wf + 8192, p.b3, p.out, p.N, 0);
}

// ---------------------------------------------------------------------------
extern "C" void kernel_launch(void* const* d_in, const int* in_sizes, int n_in,
                              void* d_out, int out_size, void* d_ws, size_t ws_size,
                              hipStream_t stream) {
    Params p;
    p.x   = (const float*)d_in[0];
    const int* ei = (const int*)d_in[1];
    p.W1l = (const float*)d_in[2];
    p.W1r = (const float*)d_in[3];
    p.W2l = (const float*)d_in[4];
    p.W2r = (const float*)d_in[5];
    p.W3l = (const float*)d_in[6];
    p.W3r = (const float*)d_in[7];
    p.b1  = (const float*)d_in[8];
    p.b2  = (const float*)d_in[9];
    p.b3  = (const float*)d_in[10];
    p.out = (float*)d_out;

    p.N = in_sizes[0] / FD;
    p.E = in_sizes[1] / 2;
    p.src = ei;
    p.dst = ei + p.E;
    p.B = (p.N + BNODES - 1) >> BSHIFT;   // 196 buckets

    char* ws = (char*)d_ws;
    size_t off = 0;
    auto alloc = [&](size_t bytes) -> void* {
        void* ptr = ws + off;
        off += (bytes + 255) & ~(size_t)255;
        return ptr;
    };
    p.deg     = (int*)alloc((size_t)p.N * 4);
    p.row_ptr = (int*)alloc((size_t)p.N * 4);
    p.rdeg    = (float*)alloc((size_t)p.N * 4);
    p.cursor  = (int*)alloc(256 * 4);
    p.bar     = (int*)alloc(64 * 4);
    p.csr     = (int*)alloc((size_t)p.B * CAP * 4);
    p.xb      = (__half*)alloc((size_t)p.N * FD * 2);
    p.h1      = (__half*)alloc((size_t)p.N * FD * 2);
    p.h2      = (__half*)alloc((size_t)p.N * FD * 2);
    p.aggB    = (__half*)alloc((size_t)p.N * FD * 2);
    p.wf      = (half8*)alloc((size_t)3 * 4096 * 16);
    p.sorted  = (int*)alloc((size_t)p.B * CAP * 4);

    hipMemsetAsync(p.bar, 0, 64 * 4, stream);
    fused_all<<<GRID, NT, 0, stream>>>(p);
}